// Round 1
// baseline (180.821 us; speedup 1.0000x reference)
//
#include <hip/hip_runtime.h>
#include <cstddef>

#define PMOD 97
#define HID 512
#define NPAIR (PMOD * PMOD)   // 9409
#define NSTEPS 15
#define PPB 16                // pairs per block in k_pairs

// ---------------------------------------------------------------------------
// Kernel A: per embedding index e (97 blocks, 512 threads):
//   Ap[e][h] = b1[h] + dot(embed[e], W1[h][0:512])
//   Bm[e][h] =         dot(embed[e], W1[h][512:1024])
// ---------------------------------------------------------------------------
__global__ __launch_bounds__(512) void k_ab(const float* __restrict__ embed,
                                            const float* __restrict__ W1,
                                            const float* __restrict__ b1,
                                            float* __restrict__ Ap,
                                            float* __restrict__ Bm) {
    __shared__ float emb[HID];
    const int e = blockIdx.x;
    const int t = threadIdx.x;   // h index
    emb[t] = embed[e * HID + t];
    __syncthreads();

    const float* row = W1 + (size_t)t * (2 * HID);
    float accA = b1[t];
    float accB = 0.f;
#pragma unroll 4
    for (int k = 0; k < HID; k += 4) {
        float4 wa = *reinterpret_cast<const float4*>(row + k);
        float4 wb = *reinterpret_cast<const float4*>(row + HID + k);
        float4 ev = *reinterpret_cast<const float4*>(&emb[k]);
        accA += wa.x * ev.x + wa.y * ev.y + wa.z * ev.z + wa.w * ev.w;
        accB += wb.x * ev.x + wb.y * ev.y + wb.z * ev.z + wb.w * ev.w;
    }
    Ap[e * HID + t] = accA;
    Bm[e * HID + t] = accB;
}

// ---------------------------------------------------------------------------
// Kernel B: one block per PPB pairs. For pair pid=(i*97+j):
//   cur1[h] = Ap[i][h] + Bm[j][h]
//   simulate 15 LIF steps per h -> wspk[h] = sum_t beta2^{14-t} * spk_t[h]
//   pairOut[pid][o] = sum_h wspk[h]*W2[o][h] + b2[o]*S,  S = sum beta2^k
// ---------------------------------------------------------------------------
__global__ __launch_bounds__(256) void k_pairs(const float* __restrict__ Ap,
                                               const float* __restrict__ Bm,
                                               const float* __restrict__ W2,
                                               const float* __restrict__ b2,
                                               const float* __restrict__ pbeta1,
                                               const float* __restrict__ pbeta2,
                                               const float* __restrict__ pthr1,
                                               float* __restrict__ pairOut) {
    __shared__ float ws[PPB][HID];   // 32 KB

    // parameter clamps (match reference)
    const float beta1 = fminf(fmaxf(pbeta1[0], 0.1f), 0.9f);  // then clip[0,1] no-op
    const float beta2 = fminf(fmaxf(pbeta2[0], 0.1f), 0.9f);
    const float thr   = fmaxf(pthr1[0], 0.1f);

    const int t = threadIdx.x;
    const int base = blockIdx.x * PPB;

    // ---- phase 1: simulate, fill ws ----
    for (int p = 0; p < PPB; ++p) {
        const int pid = base + p;
        if (pid < NPAIR) {
            const int i = pid / PMOD;
            const int j = pid - i * PMOD;
#pragma unroll
            for (int hh = 0; hh < 2; ++hh) {
                const int h = t + hh * 256;
                const float c = Ap[i * HID + h] + Bm[j * HID + h];
                float m = 0.f, w = 0.f;
#pragma unroll
                for (int s = 0; s < NSTEPS; ++s) {
                    const float r = (m > thr) ? thr : 0.f;  // reset from PREVIOUS mem
                    m = beta1 * m + c - r;
                    const float spk = (m > thr) ? 1.f : 0.f;
                    w = beta2 * w + spk;
                }
                ws[p][h] = w;
            }
        } else {
            ws[p][t] = 0.f;
            ws[p][t + 256] = 0.f;
        }
    }
    __syncthreads();

    // S = sum_{k=0..14} beta2^k, computed iteratively like the mem2 recurrence
    float S = 0.f;
#pragma unroll
    for (int s = 0; s < NSTEPS; ++s) S = beta2 * S + 1.f;

    // ---- phase 2: matvec. wave wv handles outputs o = wv, wv+4, ... ----
    const int wv = t >> 6;
    const int lane = t & 63;
    for (int o = wv; o < PMOD; o += 4) {
        const float* w2row = W2 + (size_t)o * HID + lane * 8;
        const float4 w2a = *reinterpret_cast<const float4*>(w2row);
        const float4 w2b = *reinterpret_cast<const float4*>(w2row + 4);
        const float bias = b2[o] * S;

        float acc[PPB];
#pragma unroll
        for (int p = 0; p < PPB; ++p) {
            const float* wr = &ws[p][lane * 8];
            const float4 a = *reinterpret_cast<const float4*>(wr);
            const float4 b = *reinterpret_cast<const float4*>(wr + 4);
            acc[p] = a.x * w2a.x + a.y * w2a.y + a.z * w2a.z + a.w * w2a.w
                   + b.x * w2b.x + b.y * w2b.y + b.z * w2b.z + b.w * w2b.w;
        }
#pragma unroll
        for (int p = 0; p < PPB; ++p) {
            float v = acc[p];
            v += __shfl_down(v, 32, 64);
            v += __shfl_down(v, 16, 64);
            v += __shfl_down(v, 8, 64);
            v += __shfl_down(v, 4, 64);
            v += __shfl_down(v, 2, 64);
            v += __shfl_down(v, 1, 64);
            if (lane == 0) {
                const int pid = base + p;
                if (pid < NPAIR) pairOut[(size_t)pid * PMOD + o] = v + bias;
            }
        }
    }
}

// ---------------------------------------------------------------------------
// Kernel C: out[b][o] = pairOut[x[b,0]*97 + x[b,1]][o]
// ---------------------------------------------------------------------------
__global__ __launch_bounds__(256) void k_scatter(const int* __restrict__ x,
                                                 const float* __restrict__ pairOut,
                                                 float* __restrict__ out,
                                                 int total) {
    const unsigned idx = blockIdx.x * 256u + threadIdx.x;
    if (idx >= (unsigned)total) return;
    const unsigned b = idx / PMOD;       // compiler emits magic-mul
    const unsigned o = idx - b * PMOD;
    const int pid = x[2 * b] * PMOD + x[2 * b + 1];
    out[idx] = pairOut[(size_t)pid * PMOD + o];
}

// ---------------------------------------------------------------------------
extern "C" void kernel_launch(void* const* d_in, const int* in_sizes, int n_in,
                              void* d_out, int out_size, void* d_ws, size_t ws_size,
                              hipStream_t stream) {
    const int*   x     = (const int*)d_in[0];
    const float* embed = (const float*)d_in[1];
    const float* W1    = (const float*)d_in[2];
    const float* b1    = (const float*)d_in[3];
    const float* W2    = (const float*)d_in[4];
    const float* b2    = (const float*)d_in[5];
    const float* beta1 = (const float*)d_in[6];
    const float* beta2 = (const float*)d_in[7];
    const float* thr1  = (const float*)d_in[8];
    // d_in[9] (thr2) is unused by the reference output.

    float* out = (float*)d_out;
    const int B = in_sizes[0] / 2;

    char* ws = (char*)d_ws;
    const size_t abBytes = (size_t)PMOD * HID * sizeof(float);  // 198,656 B
    float* Ap      = (float*)(ws);
    float* Bm      = (float*)(ws + abBytes);
    float* pairOut = (float*)(ws + 2 * abBytes);                // 9409*97*4 = 3.65 MB

    k_ab<<<PMOD, HID, 0, stream>>>(embed, W1, b1, Ap, Bm);

    const int nblk = (NPAIR + PPB - 1) / PPB;   // 589
    k_pairs<<<nblk, 256, 0, stream>>>(Ap, Bm, W2, b2, beta1, beta2, thr1, pairOut);

    const int total = B * PMOD;                 // 3,178,496
    k_scatter<<<(total + 255) / 256, 256, 0, stream>>>(x, pairOut, out, total);
}

// Round 2
// 100.095 us; speedup vs baseline: 1.8065x; 1.8065x over previous
//
#include <hip/hip_runtime.h>
#include <cstddef>

#define PMOD 97
#define HID 512
#define NPAIR (PMOD * PMOD)   // 9409
#define NSTEPS 15

// ---------------------------------------------------------------------------
// Kernel A: Ap[e][h] = b1[h] + dot(embed[e], W1[h][0:512])
//           Bm[e][h] =         dot(embed[e], W1[h][512:1024])
// grid = 25 e-groups x 8 h-blocks x 2 halves = 400 blocks, 256 threads.
// 4 embeds staged in LDS; each wave has a single ei -> uniform (broadcast)
// LDS reads, no bank conflicts.
// ---------------------------------------------------------------------------
__global__ __launch_bounds__(256) void k_ab(const float* __restrict__ embed,
                                            const float* __restrict__ W1,
                                            const float* __restrict__ b1,
                                            float* __restrict__ Ap,
                                            float* __restrict__ Bm) {
    __shared__ float emb[4][HID];
    const int bid = blockIdx.x;
    const int eg   = bid >> 4;        // /16 -> 0..24
    const int rem  = bid & 15;
    const int hb   = rem >> 1;        // 0..7
    const int half = rem & 1;         // 0 = A (with b1), 1 = B
    const int t = threadIdx.x;

    for (int idx = t; idx < 4 * HID; idx += 256) {
        const int ei = idx >> 9;
        const int k  = idx & 511;
        const int e  = eg * 4 + ei;
        emb[ei][k] = (e < PMOD) ? embed[e * HID + k] : 0.f;
    }
    __syncthreads();

    const int ei = t >> 6;            // wave index == embedding slot
    const int e  = eg * 4 + ei;
    if (e >= PMOD) return;
    const int h = hb * 64 + (t & 63);

    const float* row = W1 + (size_t)h * (2 * HID) + half * HID;
    float acc = half ? 0.f : b1[h];
#pragma unroll 4
    for (int k = 0; k < HID; k += 4) {
        const float4 wv = *reinterpret_cast<const float4*>(row + k);
        const float4 ev = *reinterpret_cast<const float4*>(&emb[ei][k]);
        acc += wv.x * ev.x + wv.y * ev.y + wv.z * ev.z + wv.w * ev.w;
    }
    float* dst = half ? Bm : Ap;
    dst[e * HID + h] = acc;
}

// ---------------------------------------------------------------------------
// Kernel B: 1 wave per block, 4 pairs per wave, wspk in registers (no LDS).
//   phase 1: lane owns h = lane*8..+7; simulate 15 LIF steps -> w[p][8]
//   phase 2: loop o with prefetched W2 rows; packed 64-lane butterfly
//            reduces 4 pair-dots at once; lanes 0..3 store.
// ---------------------------------------------------------------------------
__global__ __launch_bounds__(64) void k_pairs(const float* __restrict__ Ap,
                                              const float* __restrict__ Bm,
                                              const float* __restrict__ W2,
                                              const float* __restrict__ b2,
                                              const float* __restrict__ pbeta1,
                                              const float* __restrict__ pbeta2,
                                              const float* __restrict__ pthr1,
                                              float* __restrict__ pairOut) {
    const float beta1 = fminf(fmaxf(pbeta1[0], 0.1f), 0.9f);
    const float beta2 = fminf(fmaxf(pbeta2[0], 0.1f), 0.9f);
    const float thr   = fmaxf(pthr1[0], 0.1f);

    const int lane = threadIdx.x;
    const int base = blockIdx.x * 4;

    float w[4][8];
#pragma unroll
    for (int p = 0; p < 4; ++p) {
        const int pid0 = base + p;
        const int pid  = (pid0 < NPAIR) ? pid0 : (NPAIR - 1);
        const unsigned i = (unsigned)pid / PMOD;
        const unsigned j = (unsigned)pid - i * PMOD;
        const float* ap = Ap + (size_t)i * HID + lane * 8;
        const float* bp = Bm + (size_t)j * HID + lane * 8;
        const float4 a0 = *reinterpret_cast<const float4*>(ap);
        const float4 a1 = *reinterpret_cast<const float4*>(ap + 4);
        const float4 g0 = *reinterpret_cast<const float4*>(bp);
        const float4 g1 = *reinterpret_cast<const float4*>(bp + 4);
        float c[8] = {a0.x + g0.x, a0.y + g0.y, a0.z + g0.z, a0.w + g0.w,
                      a1.x + g1.x, a1.y + g1.y, a1.z + g1.z, a1.w + g1.w};
        float cm[8], m[8], sp[8];
#pragma unroll
        for (int h = 0; h < 8; ++h) {
            cm[h] = c[h] - thr;   // current when previous step spiked (reset=subtract)
            m[h] = 0.f; sp[h] = 0.f; w[p][h] = 0.f;
        }
#pragma unroll
        for (int s = 0; s < NSTEPS; ++s) {
#pragma unroll
            for (int h = 0; h < 8; ++h) {
                const float cadj = (sp[h] != 0.f) ? cm[h] : c[h];
                m[h] = fmaf(beta1, m[h], cadj);
                sp[h] = (m[h] > thr) ? 1.f : 0.f;
                w[p][h] = fmaf(beta2, w[p][h], sp[h]);
            }
        }
    }

    float S = 0.f;
#pragma unroll
    for (int s = 0; s < NSTEPS; ++s) S = fmaf(beta2, S, 1.f);

    const float* w2p = W2 + lane * 8;
    float4 ca = *reinterpret_cast<const float4*>(w2p);
    float4 cb = *reinterpret_cast<const float4*>(w2p + 4);
    float cbias = b2[0];

    for (int o = 0; o < PMOD; ++o) {
        float4 na, nb; float nbias = 0.f;
        if (o + 1 < PMOD) {
            const float* nx = w2p + (size_t)(o + 1) * HID;
            na = *reinterpret_cast<const float4*>(nx);
            nb = *reinterpret_cast<const float4*>(nx + 4);
            nbias = b2[o + 1];
        } else { na = ca; nb = cb; }

        float acc[4];
#pragma unroll
        for (int p = 0; p < 4; ++p) {
            acc[p] = w[p][0] * ca.x + w[p][1] * ca.y + w[p][2] * ca.z + w[p][3] * ca.w
                   + w[p][4] * cb.x + w[p][5] * cb.y + w[p][6] * cb.z + w[p][7] * cb.w;
        }

        // packed butterfly: 4 values -> per-lane total for p = lane&3
        const bool o1 = (lane & 1) != 0;
        const bool o2 = (lane & 2) != 0;
        float k0 = o1 ? acc[1] : acc[0];
        float s0 = o1 ? acc[0] : acc[1];
        float k1 = o1 ? acc[3] : acc[2];
        float s1 = o1 ? acc[2] : acc[3];
        k0 += __shfl_xor(s0, 1, 64);
        k1 += __shfl_xor(s1, 1, 64);
        float k2 = o2 ? k1 : k0;
        float s2 = o2 ? k0 : k1;
        k2 += __shfl_xor(s2, 2, 64);
        k2 += __shfl_xor(k2, 4, 64);
        k2 += __shfl_xor(k2, 8, 64);
        k2 += __shfl_xor(k2, 16, 64);
        k2 += __shfl_xor(k2, 32, 64);

        if (lane < 4) {
            const int pid = base + lane;
            if (pid < NPAIR) pairOut[(size_t)pid * PMOD + o] = k2 + cbias * S;
        }
        ca = na; cb = nb; cbias = nbias;
    }
}

// ---------------------------------------------------------------------------
// Kernel C: out[b][o] = pairOut[x[b,0]*97 + x[b,1]][o]
// ---------------------------------------------------------------------------
__global__ __launch_bounds__(256) void k_scatter(const int* __restrict__ x,
                                                 const float* __restrict__ pairOut,
                                                 float* __restrict__ out,
                                                 int total) {
    const unsigned idx = blockIdx.x * 256u + threadIdx.x;
    if (idx >= (unsigned)total) return;
    const unsigned b = idx / PMOD;
    const unsigned o = idx - b * PMOD;
    const int pid = x[2 * b] * PMOD + x[2 * b + 1];
    out[idx] = pairOut[(size_t)pid * PMOD + o];
}

// ---------------------------------------------------------------------------
extern "C" void kernel_launch(void* const* d_in, const int* in_sizes, int n_in,
                              void* d_out, int out_size, void* d_ws, size_t ws_size,
                              hipStream_t stream) {
    const int*   x     = (const int*)d_in[0];
    const float* embed = (const float*)d_in[1];
    const float* W1    = (const float*)d_in[2];
    const float* b1    = (const float*)d_in[3];
    const float* W2    = (const float*)d_in[4];
    const float* b2    = (const float*)d_in[5];
    const float* beta1 = (const float*)d_in[6];
    const float* beta2 = (const float*)d_in[7];
    const float* thr1  = (const float*)d_in[8];

    float* out = (float*)d_out;
    const int B = in_sizes[0] / 2;

    char* ws = (char*)d_ws;
    const size_t abBytes = (size_t)PMOD * HID * sizeof(float);
    float* Ap      = (float*)(ws);
    float* Bm      = (float*)(ws + abBytes);
    float* pairOut = (float*)(ws + 2 * abBytes);

    k_ab<<<400, 256, 0, stream>>>(embed, W1, b1, Ap, Bm);

    const int nblk = (NPAIR + 3) / 4;   // 2353 blocks, 1 wave each
    k_pairs<<<nblk, 64, 0, stream>>>(Ap, Bm, W2, b2, beta1, beta2, thr1, pairOut);

    const int total = B * PMOD;
    k_scatter<<<(total + 255) / 256, 256, 0, stream>>>(x, pairOut, out, total);
}

// Round 3
// 81.725 us; speedup vs baseline: 2.2125x; 1.2248x over previous
//
#include <hip/hip_runtime.h>
#include <cstddef>

#define PMOD 97
#define HID 512
#define NPAIR (PMOD * PMOD)   // 9409
#define NSTEPS 15

// ---------------------------------------------------------------------------
// Kernel A: Ap[e][h] = b1[h] + dot(embed[e], W1[h][0:512])
//           Bm[e][h] =         dot(embed[e], W1[h][512:1024])
// ---------------------------------------------------------------------------
__global__ __launch_bounds__(256) void k_ab(const float* __restrict__ embed,
                                            const float* __restrict__ W1,
                                            const float* __restrict__ b1,
                                            float* __restrict__ Ap,
                                            float* __restrict__ Bm) {
    __shared__ float emb[4][HID];
    const int bid = blockIdx.x;
    const int eg   = bid >> 4;        // /16 -> 0..24
    const int rem  = bid & 15;
    const int hb   = rem >> 1;        // 0..7
    const int half = rem & 1;         // 0 = A (with b1), 1 = B
    const int t = threadIdx.x;

    for (int idx = t; idx < 4 * HID; idx += 256) {
        const int ei = idx >> 9;
        const int k  = idx & 511;
        const int e  = eg * 4 + ei;
        emb[ei][k] = (e < PMOD) ? embed[e * HID + k] : 0.f;
    }
    __syncthreads();

    const int ei = t >> 6;            // wave index == embedding slot
    const int e  = eg * 4 + ei;
    if (e >= PMOD) return;
    const int h = hb * 64 + (t & 63);

    const float* row = W1 + (size_t)h * (2 * HID) + half * HID;
    float acc = half ? 0.f : b1[h];
#pragma unroll 4
    for (int k = 0; k < HID; k += 4) {
        const float4 wv = *reinterpret_cast<const float4*>(row + k);
        const float4 ev = *reinterpret_cast<const float4*>(&emb[ei][k]);
        acc += wv.x * ev.x + wv.y * ev.y + wv.z * ev.z + wv.w * ev.w;
    }
    float* dst = half ? Bm : Ap;
    dst[e * HID + h] = acc;
}

// ---------------------------------------------------------------------------
// Kernel B: 128 threads (2 waves) per 4 pairs.
//   phase 1: wave w sims pairs {2w, 2w+1} (lane owns h=lane*8..+7),
//            exchange wspk through LDS so both waves hold all 4 pairs.
//   phase 2: wave 0 -> o in [0,49), wave 1 -> o in [49,97).
//            o processed 4 at a time: 16 accs then 4 independent packed
//            butterflies (interleaved by the scheduler -> latency hidden).
// ---------------------------------------------------------------------------
__global__ __launch_bounds__(128) void k_pairs(const float* __restrict__ Ap,
                                               const float* __restrict__ Bm,
                                               const float* __restrict__ W2,
                                               const float* __restrict__ b2,
                                               const float* __restrict__ pbeta1,
                                               const float* __restrict__ pbeta2,
                                               const float* __restrict__ pthr1,
                                               float* __restrict__ pairOut) {
    __shared__ float ws[4][HID];   // 8 KB

    const float beta1 = fminf(fmaxf(pbeta1[0], 0.1f), 0.9f);
    const float beta2 = fminf(fmaxf(pbeta2[0], 0.1f), 0.9f);
    const float thr   = fmaxf(pthr1[0], 0.1f);

    const int t    = threadIdx.x;
    const int lane = t & 63;
    const int wv   = t >> 6;          // 0 or 1
    const int base = blockIdx.x * 4;

    // ---- phase 1: each wave simulates 2 pairs ----
#pragma unroll
    for (int pp = 0; pp < 2; ++pp) {
        const int p    = 2 * wv + pp;
        const int pid0 = base + p;
        const int pid  = (pid0 < NPAIR) ? pid0 : (NPAIR - 1);
        const unsigned i = (unsigned)pid / PMOD;
        const unsigned j = (unsigned)pid - i * PMOD;
        const float* ap = Ap + (size_t)i * HID + lane * 8;
        const float* bp = Bm + (size_t)j * HID + lane * 8;
        const float4 a0 = *reinterpret_cast<const float4*>(ap);
        const float4 a1 = *reinterpret_cast<const float4*>(ap + 4);
        const float4 g0 = *reinterpret_cast<const float4*>(bp);
        const float4 g1 = *reinterpret_cast<const float4*>(bp + 4);
        float c[8] = {a0.x + g0.x, a0.y + g0.y, a0.z + g0.z, a0.w + g0.w,
                      a1.x + g1.x, a1.y + g1.y, a1.z + g1.z, a1.w + g1.w};
        float cm[8], m[8], sp[8], wloc[8];
#pragma unroll
        for (int h = 0; h < 8; ++h) {
            cm[h] = c[h] - thr;
            m[h] = 0.f; sp[h] = 0.f; wloc[h] = 0.f;
        }
#pragma unroll
        for (int s = 0; s < NSTEPS; ++s) {
#pragma unroll
            for (int h = 0; h < 8; ++h) {
                const float cadj = (sp[h] != 0.f) ? cm[h] : c[h];
                m[h] = fmaf(beta1, m[h], cadj);
                sp[h] = (m[h] > thr) ? 1.f : 0.f;
                wloc[h] = fmaf(beta2, wloc[h], sp[h]);
            }
        }
        float4 lo = make_float4(wloc[0], wloc[1], wloc[2], wloc[3]);
        float4 hi = make_float4(wloc[4], wloc[5], wloc[6], wloc[7]);
        *reinterpret_cast<float4*>(&ws[p][lane * 8])     = lo;
        *reinterpret_cast<float4*>(&ws[p][lane * 8 + 4]) = hi;
    }
    __syncthreads();

    // ---- gather all 4 pairs' wspk into registers ----
    float w[4][8];
#pragma unroll
    for (int p = 0; p < 4; ++p) {
        const float4 lo = *reinterpret_cast<const float4*>(&ws[p][lane * 8]);
        const float4 hi = *reinterpret_cast<const float4*>(&ws[p][lane * 8 + 4]);
        w[p][0] = lo.x; w[p][1] = lo.y; w[p][2] = lo.z; w[p][3] = lo.w;
        w[p][4] = hi.x; w[p][5] = hi.y; w[p][6] = hi.z; w[p][7] = hi.w;
    }

    float S = 0.f;
#pragma unroll
    for (int s = 0; s < NSTEPS; ++s) S = fmaf(beta2, S, 1.f);

    const int oBeg = wv ? 49 : 0;
    const int oEnd = wv ? PMOD : 49;
    const bool o1 = (lane & 1) != 0;
    const bool o2 = (lane & 2) != 0;

    for (int ob = oBeg; ob < oEnd; ob += 4) {
        float4 wa[4], wb[4];
        float bias[4];
#pragma unroll
        for (int q = 0; q < 4; ++q) {
            const int o  = ob + q;
            const int oc = (o < PMOD) ? o : (PMOD - 1);
            const float* r = W2 + (size_t)oc * HID + lane * 8;
            wa[q] = *reinterpret_cast<const float4*>(r);
            wb[q] = *reinterpret_cast<const float4*>(r + 4);
            bias[q] = b2[oc] * S;
        }

        float red[4];
#pragma unroll
        for (int q = 0; q < 4; ++q) {
            float acc[4];
#pragma unroll
            for (int p = 0; p < 4; ++p) {
                acc[p] = w[p][0] * wa[q].x + w[p][1] * wa[q].y
                       + w[p][2] * wa[q].z + w[p][3] * wa[q].w
                       + w[p][4] * wb[q].x + w[p][5] * wb[q].y
                       + w[p][6] * wb[q].z + w[p][7] * wb[q].w;
            }
            float k0 = o1 ? acc[1] : acc[0];
            float s0 = o1 ? acc[0] : acc[1];
            float k1 = o1 ? acc[3] : acc[2];
            float s1 = o1 ? acc[2] : acc[3];
            k0 += __shfl_xor(s0, 1, 64);
            k1 += __shfl_xor(s1, 1, 64);
            float k2 = o2 ? k1 : k0;
            float s2 = o2 ? k0 : k1;
            k2 += __shfl_xor(s2, 2, 64);
            k2 += __shfl_xor(k2, 4, 64);
            k2 += __shfl_xor(k2, 8, 64);
            k2 += __shfl_xor(k2, 16, 64);
            k2 += __shfl_xor(k2, 32, 64);
            red[q] = k2;
        }

#pragma unroll
        for (int q = 0; q < 4; ++q) {
            if (lane < 4 && (ob + q) < oEnd) {
                const int pid = base + lane;
                if (pid < NPAIR)
                    pairOut[(size_t)pid * PMOD + (ob + q)] = red[q] + bias[q];
            }
        }
    }
}

// ---------------------------------------------------------------------------
// Kernel C: out[b][o] = pairOut[x[b,0]*97 + x[b,1]][o]
// ---------------------------------------------------------------------------
__global__ __launch_bounds__(256) void k_scatter(const int* __restrict__ x,
                                                 const float* __restrict__ pairOut,
                                                 float* __restrict__ out,
                                                 int total) {
    const unsigned idx = blockIdx.x * 256u + threadIdx.x;
    if (idx >= (unsigned)total) return;
    const unsigned b = idx / PMOD;
    const unsigned o = idx - b * PMOD;
    const int pid = x[2 * b] * PMOD + x[2 * b + 1];
    out[idx] = pairOut[(size_t)pid * PMOD + o];
}

// ---------------------------------------------------------------------------
extern "C" void kernel_launch(void* const* d_in, const int* in_sizes, int n_in,
                              void* d_out, int out_size, void* d_ws, size_t ws_size,
                              hipStream_t stream) {
    const int*   x     = (const int*)d_in[0];
    const float* embed = (const float*)d_in[1];
    const float* W1    = (const float*)d_in[2];
    const float* b1    = (const float*)d_in[3];
    const float* W2    = (const float*)d_in[4];
    const float* b2    = (const float*)d_in[5];
    const float* beta1 = (const float*)d_in[6];
    const float* beta2 = (const float*)d_in[7];
    const float* thr1  = (const float*)d_in[8];

    float* out = (float*)d_out;
    const int B = in_sizes[0] / 2;

    char* ws = (char*)d_ws;
    const size_t abBytes = (size_t)PMOD * HID * sizeof(float);
    float* Ap      = (float*)(ws);
    float* Bm      = (float*)(ws + abBytes);
    float* pairOut = (float*)(ws + 2 * abBytes);

    k_ab<<<400, 256, 0, stream>>>(embed, W1, b1, Ap, Bm);

    const int nblk = (NPAIR + 3) / 4;   // 2353 blocks, 2 waves each
    k_pairs<<<nblk, 128, 0, stream>>>(Ap, Bm, W2, b2, beta1, beta2, thr1, pairOut);

    const int total = B * PMOD;
    k_scatter<<<(total + 255) / 256, 256, 0, stream>>>(x, pairOut, out, total);
}